// Round 8
// baseline (115.493 us; speedup 1.0000x reference)
//
#include <hip/hip_runtime.h>
#include <hip/hip_bf16.h>
#include <math.h>

#define NN 2048
#define BB 32
#define NT 64                 // total K-dim MFMA chunk count: 2048 / 32
#define NBLK 256              // block = (osc_tile 0..127, batch_half 0..1)
#define DT_C 0.1f
#define PI_F 3.14159265358979323846f
#define TWO_PI_F 6.28318530717958647692f
#define MAGIC 0x5EED5EEDu

// ws layout (sync words line-padded):
//   EPOCH @ 0, READY @ 256, FLAG b @ 512 + 256*b (b<256)  -> ends at ~66 KB
//   (flags/epoch used ONCE, for the single mid-kernel exchange barrier)
//   ACC @ 80 KB: sin[32], cos[32] fp32 sums + arrival counter (atomic tail)
//   TABX @ 128 KB: ONE packed sincos table (theta(5) exchange), 256 KB
#define EPOCH_OFF  0
#define READY_OFF  256
#define FLAG_OFF   512
#define FLAG_STRIDE 256
#define ACC_OFF    81920
#define TAB_BASE   131072

typedef __attribute__((ext_vector_type(8))) short short8;
typedef __attribute__((ext_vector_type(4))) float floatx4;

__device__ __forceinline__ unsigned short f2bf(float x) {
    union { float f; unsigned int u; } v; v.f = x;
    unsigned int r = v.u + 0x7FFFu + ((v.u >> 16) & 1u);
    return (unsigned short)(r >> 16);
}

// sc1 write-through store / L2-bypass load (agent-coherent, no cache walks)
__device__ __forceinline__ void st_sc(unsigned int* p, unsigned int v) {
    __hip_atomic_store(p, v, __ATOMIC_RELAXED, __HIP_MEMORY_SCOPE_AGENT);
}
__device__ __forceinline__ unsigned int ld_sc(const unsigned int* p) {
    return __hip_atomic_load((unsigned int*)p, __ATOMIC_RELAXED,
                             __HIP_MEMORY_SCOPE_AGENT);
}

// R11 aggregator barrier (best-measured mechanics) — used exactly ONCE,
// for the single mid-kernel theta(5) exchange. Its entry __syncthreads
// drains each wave's vmcnt -> all TABX stores are at L3 before the flag.
__device__ __forceinline__ void gridbar(char* wsb, unsigned int tgt) {
    __syncthreads();
    unsigned int* epoch = (unsigned int*)(wsb + EPOCH_OFF);
    if (blockIdx.x == 0) {
        if (threadIdx.x == 0)
            st_sc((unsigned int*)(wsb + FLAG_OFF), tgt);
        if (threadIdx.x < 64) {
            const int lane = threadIdx.x;
            const unsigned int* f0 = (const unsigned int*)(wsb + FLAG_OFF + (size_t)(4 * lane + 0) * FLAG_STRIDE);
            const unsigned int* f1 = (const unsigned int*)(wsb + FLAG_OFF + (size_t)(4 * lane + 1) * FLAG_STRIDE);
            const unsigned int* f2 = (const unsigned int*)(wsb + FLAG_OFF + (size_t)(4 * lane + 2) * FLAG_STRIDE);
            const unsigned int* f3 = (const unsigned int*)(wsb + FLAG_OFF + (size_t)(4 * lane + 3) * FLAG_STRIDE);
            for (;;) {
                unsigned int v0 = ld_sc(f0);   // 4 independent loads: 1 RT/iter
                unsigned int v1 = ld_sc(f1);
                unsigned int v2 = ld_sc(f2);
                unsigned int v3 = ld_sc(f3);
                bool ok = (v0 >= tgt) & (v1 >= tgt) & (v2 >= tgt) & (v3 >= tgt);
                if (__all(ok)) break;
                __builtin_amdgcn_s_sleep(2);
            }
            if (lane == 0) st_sc(epoch, tgt);
        }
    } else {
        if (threadIdx.x == 0) {
            st_sc((unsigned int*)(wsb + FLAG_OFF + (size_t)blockIdx.x * FLAG_STRIDE), tgt);
            while (ld_sc(epoch) < tgt)
                __builtin_amdgcn_s_sleep(4);
        }
    }
    __syncthreads();
}

// unpack packed word pair {(s<<16)|c} x2 -> packed bf16x2 sin and cos
__device__ __forceinline__ void unpack2(unsigned int lo, unsigned int hi,
                                        unsigned int& sp, unsigned int& cp) {
    sp = __builtin_amdgcn_perm(hi, lo, 0x07060302u);  // {s1,s0}
    cp = __builtin_amdgcn_perm(hi, lo, 0x05040100u);  // {c1,c0}
}

// build two packed bf16x2 fragment words from two angles:
// us = {sin(x1),sin(x0)}, uc = {cos(x1),cos(x0)}
#define SC2(x0, x1, us, uc) do {                                   \
    float _s0, _c0, _s1, _c1;                                      \
    __sincosf((x0), &_s0, &_c0);                                   \
    __sincosf((x1), &_s1, &_c1);                                   \
    (us) = ((unsigned int)f2bf(_s1) << 16) | f2bf(_s0);            \
    (uc) = ((unsigned int)f2bf(_c1) << 16) | f2bf(_c0);            \
} while (0)

// ROUND-18: R17 (communication-avoiding, 1 exchange — verified: 57 us
// profiled, absmax in-band) widened to 8 WAVES / 512 THREADS. R17's
// residual 57 us was ~50 us of pure stall at 1 wave/SIMD: sincos chains,
// VGPR-limited staging batches, and load-use gaps all exposed wall-clock.
// 2 waves/SIMD fills those bubbles (m114: pipes co-schedule across waves):
//   - K split 8-way: 4 chunk-pairs/wave, 64 sincos/lane in GEMM-1 (was 128)
//   - staging: one 16-float4 batch per wave (was 2)
//   - waves w and w+4 redundantly update the same batch row (bit-identical
//     arithmetic); publishes/atomics gated to w<4
// Everything else verbatim from R17: phase structure (GEMM-1 from local
// theta0 sincos -> 5 frozen-P/Q steps -> ONE exchange+gridbar -> GEMM-2
// from cached table -> 5 steps), R11 barrier mechanics, atomic tail.
// Fragment layout (m89/m91-verified): A: lane holds A[m=lane&15][k=(lane>>4)*8+j];
// B mirrored; D: row(batch)=(lane>>4)*4+r, col(osc)=lane&15.
__global__ void __launch_bounds__(512, 1) kuramoto_fused(
    const float* __restrict__ theta0, const float* __restrict__ K,
    const float* __restrict__ omega, const float* __restrict__ K_global,
    const float* __restrict__ mu_gate,
    float* __restrict__ theta_out, float* __restrict__ coh,
    char* __restrict__ wsb)
{
    const int tid   = threadIdx.x;
    const int w     = tid >> 6;             // wave id = K-eighth 0..7
    const int lane  = tid & 63;
    const int lrow  = lane & 15;
    const int kq    = lane >> 4;            // 0..3
    const int tile  = blockIdx.x >> 1;
    const int bh    = blockIdx.x & 1;       // batch half
    const int i0    = tile * 16;
    const int b0    = bh * 16;
    const int i     = i0 + lrow;
    const int qbase = w * 8;                // first chunk of this wave's eighth

    // one-time: drop pre-kernel (poison) lines from local caches before any
    // cached table read (belt-and-braces alongside launch acquire)
    __builtin_amdgcn_fence(__ATOMIC_ACQUIRE, "agent");

    // block 0 zeroes the (poisoned) barrier words + tail accumulators.
    // Ordering to everyone else is via the READY handshake pre-gridbar.
    if (blockIdx.x == 0) {
        if (tid < 256)
            st_sc((unsigned int*)(wsb + FLAG_OFF + (size_t)tid * FLAG_STRIDE), 0u);
        if (tid < 66)                       // sin[32] cos[32] cnt (+pad)
            st_sc((unsigned int*)(wsb + ACC_OFF) + tid, 0u);
        if (tid == 0)
            st_sc((unsigned int*)(wsb + EPOCH_OFF), 0u);
    }

    unsigned int* TABX = (unsigned int*)(wsb + TAB_BASE);

    const float coefdt = K_global[0] * (DT_C / (float)NN);  // DT folded in

    // ---- K staging: issue this wave's 16 float4 loads FIRST ----
    __shared__ short8 kb[NT * 64];          // 64 KB, kb[t*64 + lane]
    __shared__ floatx4 red[8][2][64];       // 16 KB: [wave][P/Q][lane]
    float4 buf[16];
    #pragma unroll
    for (int j = 0; j < 8; ++j) {
        const float4* kp = (const float4*)(K + (size_t)i * NN + (qbase + j) * 32 + kq * 8);
        buf[2 * j]     = kp[0];
        buf[2 * j + 1] = kp[1];
    }

    // while staging is in flight: own theta + omega + sincos.
    // this thread owns theta[row = b0+4*kq+(w&3)][osc col = i]
    // (waves w and w+4 duplicate the row — bit-identical arithmetic)
    const size_t myoff = (size_t)(b0 + kq * 4 + (w & 3)) * NN + i;
    const float om_dt = omega[i] * DT_C;
    float th0 = theta0[myoff], sb0, cb0;
    __sincosf(th0, &sb0, &cb0);

    // convert staged K to pre-scaled bf16 B-fragments
    const float kscale = mu_gate[0] * 0.5f; // MU_BRANCH_SCALE fold
    #pragma unroll
    for (int j = 0; j < 8; ++j) {
        float4 x = buf[2 * j], y = buf[2 * j + 1];
        short8 f;
        f[0] = (short)f2bf(x.x * kscale); f[1] = (short)f2bf(x.y * kscale);
        f[2] = (short)f2bf(x.z * kscale); f[3] = (short)f2bf(x.w * kscale);
        f[4] = (short)f2bf(y.x * kscale); f[5] = (short)f2bf(y.y * kscale);
        f[6] = (short)f2bf(y.z * kscale); f[7] = (short)f2bf(y.w * kscale);
        kb[(qbase + j) * 64 + lane] = f;
    }
    // NOTE: no __syncthreads needed before GEMM-1 — each wave reads ONLY
    // its own staged K-eighth (wave-private LDS; compiler orders lgkmcnt).

    // ---- phase 1: GEMM-1 with self-computed A-fragments from theta0 ----
    // A row m = lane&15 -> batch row b0+lrow; lane's oscillators for chunk
    // t are j = 32t + 8*kq .. +7. sincos computed directly into fragment
    // layout — no table, no exchange (theta0 is a coherent kernel input).
    const float* T0 = theta0 + (size_t)(b0 + lrow) * NN;
    floatx4 p0 = {0.f,0.f,0.f,0.f}, p1 = {0.f,0.f,0.f,0.f};
    floatx4 q0 = {0.f,0.f,0.f,0.f}, q1 = {0.f,0.f,0.f,0.f};
    #pragma unroll
    for (int c = 0; c < 4; ++c) {
        const int t = qbase + 2 * c;
        float4 ta0 = *(const float4*)(T0 + 32 * t + 8 * kq);
        float4 ta1 = *(const float4*)(T0 + 32 * t + 8 * kq + 4);
        float4 tb0 = *(const float4*)(T0 + 32 * (t + 1) + 8 * kq);
        float4 tb1 = *(const float4*)(T0 + 32 * (t + 1) + 8 * kq + 4);
        union { short8 v; unsigned int u[4]; } as0, ac0, as1, ac1;
        SC2(ta0.x, ta0.y, as0.u[0], ac0.u[0]);
        SC2(ta0.z, ta0.w, as0.u[1], ac0.u[1]);
        SC2(ta1.x, ta1.y, as0.u[2], ac0.u[2]);
        SC2(ta1.z, ta1.w, as0.u[3], ac0.u[3]);
        SC2(tb0.x, tb0.y, as1.u[0], ac1.u[0]);
        SC2(tb0.z, tb0.w, as1.u[1], ac1.u[1]);
        SC2(tb1.x, tb1.y, as1.u[2], ac1.u[2]);
        SC2(tb1.z, tb1.w, as1.u[3], ac1.u[3]);
        short8 bk0 = kb[t * 64 + lane];
        short8 bk1 = kb[(t + 1) * 64 + lane];
        p0 = __builtin_amdgcn_mfma_f32_16x16x32_bf16(as0.v, bk0, p0, 0, 0, 0);
        q0 = __builtin_amdgcn_mfma_f32_16x16x32_bf16(ac0.v, bk0, q0, 0, 0, 0);
        p1 = __builtin_amdgcn_mfma_f32_16x16x32_bf16(as1.v, bk1, p1, 0, 0, 0);
        q1 = __builtin_amdgcn_mfma_f32_16x16x32_bf16(ac1.v, bk1, q1, 0, 0, 0);
    }

    // 8-way K-split reduction via LDS: wave v publishes full P,Q; each
    // wave then sums element [w&3] of all eight slots (its row's totals).
    float Pw, Qw;
    red[w][0][lane] = p0 + p1;
    red[w][1][lane] = q0 + q1;
    __syncthreads();
    {
        // flat float idx: v*512 + pq*256 + lane*4 + e   (e = w&3)
        const float* rf = (const float*)red + lane * 4 + (w & 3);
        Pw = 0.f; Qw = 0.f;
        #pragma unroll
        for (int v = 0; v < 8; ++v) {
            Pw += rf[v * 512];
            Qw += rf[v * 512 + 256];
        }
    }

    // one frozen-P/Q local step (exact for step 1, <=4-step-stale after)
    #define LSTEP() do {                                           \
        float coup = cb0 * Pw - sb0 * Qw;                          \
        float tn = th0 + om_dt + coefdt * coup;                    \
        if (tn > PI_F)        tn -= TWO_PI_F;                      \
        else if (tn <= -PI_F) tn += TWO_PI_F;                      \
        th0 = tn; __sincosf(tn, &sb0, &cb0);                       \
    } while (0)

    LSTEP(); LSTEP(); LSTEP(); LSTEP(); LSTEP();    // theta(0) -> theta(5)

    // ---- the ONE exchange: publish packed sincos(theta5), barrier ----
    if (w < 4)
        st_sc(&TABX[myoff], ((unsigned int)f2bf(sb0) << 16) | f2bf(cb0));
    __syncthreads();                        // (drains earlier stores too)
    if (tid == 0) {
        unsigned int* ready = (unsigned int*)(wsb + READY_OFF);
        if (blockIdx.x == 0) {
            st_sc(ready, MAGIC);            // block0 zeros drained above
        } else {
            while (ld_sc(ready) != MAGIC)   // zeros visible before our flag
                __builtin_amdgcn_s_sleep(8);
        }
    }
    gridbar(wsb, 1u);                       // TABX grid-visible

    // ---- phase 2: GEMM-2 from the exchanged table (cached loads) ----
    // Lines first-touched after the barrier; start-of-kernel acquire fence
    // invalidated stale prior-dispatch copies (R14-proven pattern).
    const uint4* U = (const uint4*)(TABX + (size_t)(b0 + lrow) * NN);
    p0 = floatx4{0.f,0.f,0.f,0.f}; p1 = floatx4{0.f,0.f,0.f,0.f};
    q0 = floatx4{0.f,0.f,0.f,0.f}; q1 = floatx4{0.f,0.f,0.f,0.f};
    #pragma unroll
    for (int c = 0; c < 4; ++c) {
        const int t  = qbase + 2 * c;
        const int a0 = 8 * t + 2 * kq;      // uint4 idx: words j0..j0+7
        uint4 ua = U[a0];
        uint4 ub = U[a0 + 1];
        uint4 va = U[a0 + 8];               // chunk t+1
        uint4 vb = U[a0 + 9];
        union { short8 v; unsigned int u[4]; } as0, ac0, as1, ac1;
        unpack2(ua.x, ua.y, as0.u[0], ac0.u[0]);
        unpack2(ua.z, ua.w, as0.u[1], ac0.u[1]);
        unpack2(ub.x, ub.y, as0.u[2], ac0.u[2]);
        unpack2(ub.z, ub.w, as0.u[3], ac0.u[3]);
        unpack2(va.x, va.y, as1.u[0], ac1.u[0]);
        unpack2(va.z, va.w, as1.u[1], ac1.u[1]);
        unpack2(vb.x, vb.y, as1.u[2], ac1.u[2]);
        unpack2(vb.z, vb.w, as1.u[3], ac1.u[3]);
        short8 bk0 = kb[t * 64 + lane];
        short8 bk1 = kb[(t + 1) * 64 + lane];
        p0 = __builtin_amdgcn_mfma_f32_16x16x32_bf16(as0.v, bk0, p0, 0, 0, 0);
        q0 = __builtin_amdgcn_mfma_f32_16x16x32_bf16(ac0.v, bk0, q0, 0, 0, 0);
        p1 = __builtin_amdgcn_mfma_f32_16x16x32_bf16(as1.v, bk1, p1, 0, 0, 0);
        q1 = __builtin_amdgcn_mfma_f32_16x16x32_bf16(ac1.v, bk1, q1, 0, 0, 0);
    }

    // second reduction (red reuse is WAR-safe: gridbar's barriers sit
    // between every wave's phase-1 read and this write)
    red[w][0][lane] = p0 + p1;
    red[w][1][lane] = q0 + q1;
    __syncthreads();
    {
        const float* rf = (const float*)red + lane * 4 + (w & 3);
        Pw = 0.f; Qw = 0.f;
        #pragma unroll
        for (int v = 0; v < 8; ++v) {
            Pw += rf[v * 512];
            Qw += rf[v * 512 + 256];
        }
    }

    LSTEP(); LSTEP(); LSTEP(); LSTEP(); LSTEP();    // theta(5) -> theta(10)
    #undef LSTEP

    if (w < 4)
        theta_out[myoff] = th0;             // wrapped final theta

    // ---- atomic coherence tail ----
    // Each lane of waves w<4 holds fp32 sin/cos of final theta for row
    // b0+kq*4+w, col i. Butterfly all-reduce over the 16 osc lanes of each
    // kq group, then lanes j<2 publish one f32 atomic each (32 adds/block).
    #pragma unroll
    for (int m = 1; m < 16; m <<= 1) {
        sb0 += __shfl_xor(sb0, m, 64);
        cb0 += __shfl_xor(cb0, m, 64);
    }
    {
        float* sacc = (float*)(wsb + ACC_OFF);
        float* cacc = sacc + 32;
        const int j = lane & 15;
        if (w < 4 && j < 2) {
            const int row = b0 + kq * 4 + w;
            float  val = (j == 0) ? sb0 : cb0;
            float* dst = (j == 0) ? (sacc + row) : (cacc + row);
            __hip_atomic_fetch_add(dst, val, __ATOMIC_RELAXED,
                                   __HIP_MEMORY_SCOPE_AGENT);
        }
        __syncthreads();                    // drains all waves' atomics
        if (w == 0) {
            unsigned int old = 0u;
            if (lane == 0) {
                unsigned int* cnt = (unsigned int*)(sacc + 64);
                old = __hip_atomic_fetch_add(cnt, 1u, __ATOMIC_ACQ_REL,
                                             __HIP_MEMORY_SCOPE_AGENT);
            }
            const int islast = __shfl((int)(old == NBLK - 1), 0, 64);
            if (islast) {                   // 256th arrival: all sums at L3
                __builtin_amdgcn_fence(__ATOMIC_ACQUIRE, "agent");
                if (lane < BB) {
                    float s = __hip_atomic_load(sacc + lane, __ATOMIC_RELAXED,
                                                __HIP_MEMORY_SCOPE_AGENT);
                    float c = __hip_atomic_load(cacc + lane, __ATOMIC_RELAXED,
                                                __HIP_MEMORY_SCOPE_AGENT);
                    float sm = s * (1.0f / NN), cm = c * (1.0f / NN);
                    coh[lane] = sqrtf(sm * sm + cm * cm);
                }
            }
        }
    }
}

extern "C" void kernel_launch(void* const* d_in, const int* in_sizes, int n_in,
                              void* d_out, int out_size, void* d_ws, size_t ws_size,
                              hipStream_t stream)
{
    const float* theta0   = (const float*)d_in[0];   // 32*2048
    const float* K        = (const float*)d_in[1];   // 2048*2048
    const float* omega    = (const float*)d_in[2];   // 2048
    const float* K_global = (const float*)d_in[3];   // 1
    const float* mu_gate  = (const float*)d_in[4];   // 1

    float* theta_out = (float*)d_out;                // 65536 floats
    float* coh       = theta_out + BB * NN;          // 32 floats

    // ws needs ~384 KB: 128 KB sync region + one 256 KB exchange table
    kuramoto_fused<<<dim3(NBLK), dim3(512), 0, stream>>>(
        theta0, K, omega, K_global, mu_gate, theta_out, coh, (char*)d_ws);
}